// Round 7
// baseline (2874.240 us; speedup 1.0000x reference)
//
#include <hip/hip_runtime.h>
#include <math.h>

#define S_   56
#define B_   32
#define C_   1024
#define T_   48
#define TS   47
#define H_   1024
#define EMB_ 512
#define RANK_ 128
#define VOCAB_ 32000
#define G4   4096
#define NBLK 128
#define NVC  500

using bf16x8 = __attribute__((ext_vector_type(8))) __bf16;
using f32x4  = __attribute__((ext_vector_type(4))) float;

__device__ __forceinline__ float sigmoidf_(float x){ return 1.0f/(1.0f+expf(-x)); }
__device__ __forceinline__ float b2f(__bf16 x){ return (float)x; }

// ---------- device-coherent (MALL-visible) access helpers ----------
#define AG __HIP_MEMORY_SCOPE_AGENT
__device__ __forceinline__ bf16x8 ldc16(const __bf16* p){
  union { unsigned long long u[2]; bf16x8 v; } t;
  t.u[0] = __hip_atomic_load((const unsigned long long*)p,     __ATOMIC_RELAXED, AG);
  t.u[1] = __hip_atomic_load((const unsigned long long*)(p+4), __ATOMIC_RELAXED, AG);
  return t.v;
}
__device__ __forceinline__ void stc_u64(void* p, unsigned long long v){
  __hip_atomic_store((unsigned long long*)p, v, __ATOMIC_RELAXED, AG);
}
__device__ __forceinline__ void stc_bf16(__bf16* p, __bf16 v){
  union { __bf16 b; unsigned short s; } t; t.b = v;
  __hip_atomic_store((unsigned short*)p, t.s, __ATOMIC_RELAXED, AG);
}

// ---------------- shared-memory union for the persistent kernel ----------------
struct GemmShared {
  float  Gp[2][3][32][17];   // partials from kq=1..3
  float  Gs[32][33];
};
struct AttnShared {
  float sS[64];
  float pS[64];
  float cred[16][32][8];
};
union alignas(16) SharedU { GemmShared g; AttnShared a; };

// ---------------- hierarchical grid barrier (monotonic, relaxed) ----------------
__device__ __forceinline__ void grid_bar(unsigned* bars, int bi, unsigned e){
  asm volatile("s_waitcnt vmcnt(0)" ::: "memory");
  __syncthreads();
  if (threadIdx.x == 0){
    unsigned* grp = bars + 32*(1 + (bi & 7));
    unsigned old = __hip_atomic_fetch_add(grp, 1u, __ATOMIC_RELAXED, AG);
    if (old == 16u*e - 1u)
      __hip_atomic_fetch_add(bars, 1u, __ATOMIC_RELAXED, AG);
    while (__hip_atomic_load(bars, __ATOMIC_RELAXED, AG) < 8u*e)
      __builtin_amdgcn_s_sleep(1);
  }
  __syncthreads();
}

// ---------------- init ----------------
__global__ void k_init(const float* __restrict__ es, __bf16* xa0a, __bf16* xa1a,
                       float* c0, float* c1, unsigned* bars){
  int i = blockIdx.x*blockDim.x + threadIdx.x;
  if (i < 32*H_){
    int b = i >> 10, j = i & 1023;
    xa0a[(size_t)b*2560 + 1536 + j] = (__bf16)es[i];           // h0 <- es[0]
    xa0a[(size_t)b*2560 + 512  + j] = (__bf16)0.0f;            // ctx = 0
    xa1a[(size_t)b*2048 + 1024 + j] = (__bf16)es[32*H_ + i];   // h1 <- es[1]
    c0[i] = 0.f; c1[i] = 0.f;
  }
  if (i < 512) bars[i] = 0u;
}

// ---------------- fp32 -> bf16 ----------------
__global__ void k_cvt(const float* __restrict__ src, __bf16* __restrict__ dst, int n){
  int i = (blockIdx.x*blockDim.x + threadIdx.x)*4;
  if (i < n){
    float4 v = *(const float4*)(src + i);
    dst[i+0]=(__bf16)v.x; dst[i+1]=(__bf16)v.y; dst[i+2]=(__bf16)v.z; dst[i+3]=(__bf16)v.w;
  }
}

// ---------------- embedding ----------------
__global__ void k_embed(const float* __restrict__ E, const float* __restrict__ P,
                        const int* __restrict__ tok, __bf16* __restrict__ embb,
                        __bf16* __restrict__ xa0a){
  int blk = blockIdx.x;            // t*32+b
  int t = blk >> 5, b = blk & 31, tid = threadIdx.x;   // 128 threads
  __shared__ float er[RANK_];
  int tk = tok[b*T_ + t];
  er[tid] = E[(size_t)tk*RANK_ + tid];
  __syncthreads();
  float4 acc = {0.f,0.f,0.f,0.f};
  int e = tid*4;
  for (int r2 = 0; r2 < RANK_; r2++){
    float ev = er[r2];
    float4 p = *(const float4*)(P + (size_t)r2*EMB_ + e);
    acc.x += ev*p.x; acc.y += ev*p.y; acc.z += ev*p.z; acc.w += ev*p.w;
  }
  size_t o = (size_t)blk*EMB_ + e;
  embb[o+0]=(__bf16)acc.x; embb[o+1]=(__bf16)acc.y;
  embb[o+2]=(__bf16)acc.z; embb[o+3]=(__bf16)acc.w;
  if (t == 0){
    size_t o2 = (size_t)b*2560 + e;
    xa0a[o2+0]=(__bf16)acc.x; xa0a[o2+1]=(__bf16)acc.y;
    xa0a[o2+2]=(__bf16)acc.z; xa0a[o2+3]=(__bf16)acc.w;
  }
}

// ---------------- pack [W;U] into MFMA B-fragment order (4 k-quarters) ----------------
__global__ void k_pack(const float* __restrict__ W, int K1, const float* __restrict__ U,
                       __bf16* __restrict__ dst, int K, int NCHQ){
  int kk0 = blockIdx.x*32, j0 = blockIdx.y*64, tid = threadIdx.x;
  __shared__ __bf16 Tl[32][72];
  {
    int r = tid>>3, cp = tid&7;
    int kk = kk0 + r;
    const float* src = (kk < K1) ? (W + (size_t)kk*G4 + j0 + cp*8)
                                 : (U + (size_t)(kk-K1)*G4 + j0 + cp*8);
    float4 v0 = *(const float4*)(src);
    float4 v1 = *(const float4*)(src+4);
    Tl[r][cp*8+0]=(__bf16)v0.x; Tl[r][cp*8+1]=(__bf16)v0.y;
    Tl[r][cp*8+2]=(__bf16)v0.z; Tl[r][cp*8+3]=(__bf16)v0.w;
    Tl[r][cp*8+4]=(__bf16)v1.x; Tl[r][cp*8+5]=(__bf16)v1.y;
    Tl[r][cp*8+6]=(__bf16)v1.z; Tl[r][cp*8+7]=(__bf16)v1.w;
  }
  __syncthreads();
  int jl = tid&63, q = tid>>6;
  __bf16 out8[8];
  #pragma unroll
  for (int i=0;i<8;i++) out8[i] = Tl[q*8+i][jl];
  int j = j0 + jl;
  int g = j>>10, gp = g>>1, gbit = g&1;
  int bi = (j&1023)>>3, jlo = j&7;
  int KQ = K/4;
  int kq = kk0 / KQ, ch = (kk0 % KQ) >> 5;
  int lane = q*16 + gbit*8 + jlo;
  size_t off = ((((size_t)(bi*2+gp)*4 + kq)*NCHQ + ch)*64 + lane)*8;
  *(bf16x8*)(dst + off) = *(bf16x8*)out8;
}

// ---------------- generic B-frag pack (16x16x32) for Wo / P^T ----------------
__global__ void k_packB(const float* __restrict__ src, __bf16* __restrict__ dst,
                        int K, int N, int tr){
  int kk0 = blockIdx.x*32, j0 = blockIdx.y*16, lane = threadIdx.x;  // 64 threads
  int am = lane&15, aq = lane>>4;
  int j = j0 + am;
  __bf16 o8[8];
  #pragma unroll
  for (int i=0;i<8;i++){
    int k = kk0 + aq*8 + i;
    float v = tr ? src[(size_t)j*K + k] : src[(size_t)k*N + j];
    o8[i] = (__bf16)v;
  }
  int NCH = K/32, jt = j0>>4, ch = kk0>>5;
  *(bf16x8*)(dst + (((size_t)jt*NCH + ch)*64 + lane)*8) = *(bf16x8*)o8;
}

// ---------------- fused gates GEMM + LSTM cell (sync-free K-loop) ----------------
// Each wave loads its own A-fragments (registers, MFMA layout) -> no LDS staging,
// no __syncthreads in the K-loop; waves slip freely for latency hiding.
template<int K, int NCHQ>
__device__ __forceinline__ void gemm_cell(GemmShared& sgm, int bi, int tid,
    const __bf16* __restrict__ xa_in, const __bf16* __restrict__ WP,
    const float* __restrict__ bias, float* __restrict__ cst,
    __bf16* __restrict__ hout0, int stride0, int off0,
    __bf16* __restrict__ hout1, int stride1, int off1,
    __bf16* __restrict__ houtf, int stridef, int offf)
{
  constexpr int KQ = K/4;
  int w = tid>>6, lane = tid&63;
  int gp = w&1, kq = w>>1;                  // gate-pair, k-quarter
  int am = lane&15, aq = lane>>4;
  f32x4 acc0 = {0,0,0,0}, acc1 = {0,0,0,0};

  const __bf16* aptr0 = xa_in + (size_t)am*K + kq*KQ + aq*8;       // A row am
  const __bf16* aptr1 = aptr0 + (size_t)16*K;                      // A row am+16
  const __bf16* bptr  = WP + ((((size_t)bi*2 + gp)*4 + kq)*NCHQ)*512 + lane*8;

  bf16x8 a0r[4], a1r[4], br[4];
  #pragma unroll
  for (int i=0;i<4;i++){
    a0r[i] = ldc16(aptr0 + (size_t)i*32);
    a1r[i] = ldc16(aptr1 + (size_t)i*32);
    br[i]  = *(const bf16x8*)(bptr + (size_t)i*512);
  }

  #pragma unroll 4
  for (int ch = 0; ch < NCHQ; ch++){
    int slot = ch & 3;
    bf16x8 a0 = a0r[slot], a1 = a1r[slot], bb = br[slot];
    if (ch + 4 < NCHQ){
      a0r[slot] = ldc16(aptr0 + (size_t)(ch+4)*32);
      a1r[slot] = ldc16(aptr1 + (size_t)(ch+4)*32);
      br[slot]  = *(const bf16x8*)(bptr + (size_t)(ch+4)*512);
    }
    acc0 = __builtin_amdgcn_mfma_f32_16x16x32_bf16(a0, bb, acc0, 0, 0, 0);
    acc1 = __builtin_amdgcn_mfma_f32_16x16x32_bf16(a1, bb, acc1, 0, 0, 0);
  }

  if (kq > 0){
    #pragma unroll
    for (int rg=0; rg<4; rg++){
      sgm.Gp[gp][kq-1][aq*4+rg][am]    = acc0[rg];
      sgm.Gp[gp][kq-1][16+aq*4+rg][am] = acc1[rg];
    }
  }
  __syncthreads();
  if (kq == 0){
    #pragma unroll
    for (int rg=0; rg<4; rg++){
      int r0 = aq*4+rg, r1 = 16+aq*4+rg;
      sgm.Gs[r0][gp*16+am] = acc0[rg] + sgm.Gp[gp][0][r0][am]
                           + sgm.Gp[gp][1][r0][am] + sgm.Gp[gp][2][r0][am];
      sgm.Gs[r1][gp*16+am] = acc1[rg] + sgm.Gp[gp][0][r1][am]
                           + sgm.Gp[gp][1][r1][am] + sgm.Gp[gp][2][r1][am];
    }
  }
  __syncthreads();
  if (tid < 256){
    int b = tid>>3, hd = tid&7;
    int j = bi*8 + hd;
    float gi = sgm.Gs[b][hd]     + bias[j];
    float gf = sgm.Gs[b][8+hd]   + bias[1024 + j];
    float gg = sgm.Gs[b][16+hd]  + bias[2048 + j];
    float go = sgm.Gs[b][24+hd]  + bias[3072 + j];
    float ii = sigmoidf_(gi), ff = sigmoidf_(gf), gv = tanhf(gg), oo = sigmoidf_(go);
    float cv = ff*cst[b*1024 + j] + ii*gv;
    float hv = oo*tanhf(cv);
    cst[b*1024 + j] = cv;
    stc_bf16(hout0 + (size_t)b*stride0 + off0 + j, (__bf16)hv);
    if (hout1) stc_bf16(hout1 + (size_t)b*stride1 + off1 + j, (__bf16)hv);
    if (houtf) stc_bf16(houtf + (size_t)b*stridef + offf + j, (__bf16)hv);
  }
}

// ---------------- attention: 128 blocks = 32 b-rows x 4 C-quarters ----------------
__device__ __forceinline__ void attn_block(AttnShared& sa, int b, int cq, int tid,
    const __bf16* __restrict__ encb, const int* __restrict__ enc_lens,
    __bf16* __restrict__ fbt, __bf16* __restrict__ xa0q,
    const __bf16* __restrict__ embnext)
{
  int w = tid >> 6, lane = tid & 63;
  // h1 row b fragments in registers: lane holds cols [lane*16, lane*16+16)
  bf16x8 hr0 = ldc16(fbt + (size_t)b*2048 + lane*16);
  bf16x8 hr1 = ldc16(fbt + (size_t)b*2048 + lane*16 + 8);
  // scores: wave w handles s = w, w+8, ..., w+48
  for (int s = w; s < S_; s += 8){
    const __bf16* er = encb + ((size_t)s*32 + b)*C_ + lane*16;
    bf16x8 e0 = *(const bf16x8*)(er);
    bf16x8 e1 = *(const bf16x8*)(er + 8);
    float a = 0.f;
    #pragma unroll
    for (int u=0;u<8;u++) a += b2f(e0[u])*b2f(hr0[u]) + b2f(e1[u])*b2f(hr1[u]);
    #pragma unroll
    for (int off=32; off>0; off>>=1) a += __shfl_down(a, off);
    if (lane == 0) sa.sS[s] = a;
  }
  __syncthreads();
  if (tid < 64){
    int len = enc_lens[b];
    float sc = (tid < len && tid < S_) ? sa.sS[tid] : -1e30f;
    float m = sc;
    #pragma unroll
    for (int off=32; off>0; off>>=1) m = fmaxf(m, __shfl_xor(m, off));
    float e = expf(sc - m);
    float ssum = e;
    #pragma unroll
    for (int off=32; off>0; off>>=1) ssum += __shfl_xor(ssum, off);
    sa.pS[tid] = e / ssum;
  }
  __syncthreads();
  // ctx over this block's C-quarter [cq*256, cq*256+256): 32 col-groups x 16 s-groups
  int cg = tid & 31, sg = tid >> 5;
  float a8[8];
  #pragma unroll
  for (int i=0;i<8;i++) a8[i] = 0.f;
  for (int s = sg; s < S_; s += 16){
    float p = sa.pS[s];
    bf16x8 e8 = *(const bf16x8*)(encb + ((size_t)s*32 + b)*C_ + cq*256 + cg*8);
    #pragma unroll
    for (int i=0;i<8;i++) a8[i] += p * b2f(e8[i]);
  }
  #pragma unroll
  for (int i=0;i<8;i++) sa.cred[sg][cg][i] = a8[i];
  __syncthreads();
  if (tid < 32){
    union { __bf16 bb[8]; unsigned long long u[2]; } cu;
    #pragma unroll
    for (int i=0;i<8;i++){
      float v = 0.f;
      #pragma unroll
      for (int s2=0;s2<16;s2++) v += sa.cred[s2][tid][i];
      cu.bb[i] = (__bf16)v;
    }
    size_t coff = cq*256 + tid*8;
    stc_u64(xa0q + (size_t)b*2560 + 512 + coff,     cu.u[0]);
    stc_u64(xa0q + (size_t)b*2560 + 512 + coff + 4, cu.u[1]);
    stc_u64(fbt + (size_t)b*2048 + 1024 + coff,     cu.u[0]);
    stc_u64(fbt + (size_t)b*2048 + 1024 + coff + 4, cu.u[1]);
  }
  if (embnext && cq == 0 && tid < 64){
    union { bf16x8 v; unsigned long long u[2]; } t;
    t.v = *(const bf16x8*)(embnext + (size_t)b*512 + tid*8);
    stc_u64(xa0q + (size_t)b*2560 + tid*8,     t.u[0]);
    stc_u64(xa0q + (size_t)b*2560 + tid*8 + 4, t.u[1]);
  }
}

// ---------------- persistent decode loop (128 blocks x 512 threads) ----------------
__global__ __launch_bounds__(512) void k_loop(
    const __bf16* __restrict__ WP0, const __bf16* __restrict__ WP1,
    const float* __restrict__ b0, const float* __restrict__ b1,
    float* __restrict__ c0, float* __restrict__ c1,
    __bf16* xa0a, __bf16* xa0b, __bf16* xa1a, __bf16* xa1b,
    const __bf16* __restrict__ encb, const int* __restrict__ enc_lens,
    const __bf16* __restrict__ embb, __bf16* __restrict__ featsb,
    unsigned* bars)
{
  __shared__ SharedU su;
  int bi = blockIdx.x, tid = threadIdx.x;
  unsigned bcount = 0;
  __bf16* xa0[2] = {xa0a, xa0b};
  __bf16* xa1[2] = {xa1a, xa1b};

  for (int t = 0; t < TS; t++){
    int p = t & 1, q = p ^ 1;
    gemm_cell<2560,20>(su.g, bi, tid, xa0[p], WP0, b0, c0,
                       xa1[p], 2048, 0,
                       xa0[q], 2560, 1536,
                       (__bf16*)nullptr, 0, 0);
    grid_bar(bars, bi, ++bcount);
    gemm_cell<2048,16>(su.g, bi, tid, xa1[p], WP1, b1, c1,
                       xa1[q], 2048, 1024,
                       (__bf16*)nullptr, 0, 0,
                       featsb + (size_t)t*32*2048, 2048, 0);
    grid_bar(bars, bi, ++bcount);
    attn_block(su.a, bi & 31, bi >> 5, tid, encb, enc_lens,
               featsb + (size_t)t*32*2048, xa0[q],
               (t+1 < TS) ? (embb + (size_t)(t+1)*32*EMB_) : (const __bf16*)nullptr);
    grid_bar(bars, bi, ++bcount);
  }
}

// ---------------- hproj = tanh(featsb @ WoP + bo) -> hpb (bf16 MFMA) ----------------
__global__ __launch_bounds__(256) void k_hproj_mfma(
    const __bf16* __restrict__ fb, const __bf16* __restrict__ WoP,
    const float* __restrict__ bo, __bf16* __restrict__ hpb)
{
  int nt = blockIdx.x, jb = blockIdx.y, tid = threadIdx.x;  // (47,16)
  int w = tid>>6, lane = tid&63;
  int mt = w&1, jw = w>>1;
  int am = lane&15, aq = lane>>4;
  const __bf16* aRow = fb + ((size_t)(nt*32 + mt*16 + am))*2048 + aq*8;
  int jt = jb*2 + jw;
  const __bf16* bptr = WoP + ((size_t)jt*64)*512 + lane*8;
  f32x4 acc = {0,0,0,0};
  bf16x8 ar0 = *(const bf16x8*)(aRow);
  bf16x8 br0 = *(const bf16x8*)(bptr);
  bf16x8 ar1 = *(const bf16x8*)(aRow + 32);
  bf16x8 br1 = *(const bf16x8*)(bptr + 512);
  for (int ch = 0; ch < 64; ch += 2){
    bf16x8 a0 = ar0, b0 = br0, a1 = ar1, b1 = br1;
    if (ch + 2 < 64){
      ar0 = *(const bf16x8*)(aRow + (ch+2)*32);
      br0 = *(const bf16x8*)(bptr + (size_t)(ch+2)*512);
      ar1 = *(const bf16x8*)(aRow + (ch+3)*32);
      br1 = *(const bf16x8*)(bptr + (size_t)(ch+3)*512);
    }
    acc = __builtin_amdgcn_mfma_f32_16x16x32_bf16(a0, b0, acc, 0, 0, 0);
    acc = __builtin_amdgcn_mfma_f32_16x16x32_bf16(a1, b1, acc, 0, 0, 0);
  }
  int jcol = jb*32 + jw*16 + am;
  float bv = bo[jcol];
  #pragma unroll
  for (int rg=0; rg<4; rg++){
    int m = nt*32 + mt*16 + aq*4 + rg;
    hpb[(size_t)m*512 + jcol] = (__bf16)tanhf(acc[rg] + bv);
  }
}

// ---------------- r = hpb @ P^T -> rbuf (bf16 MFMA) ----------------
__global__ __launch_bounds__(256) void k_rproj_mfma(
    const __bf16* __restrict__ hpb, const __bf16* __restrict__ PP,
    __bf16* __restrict__ rb)
{
  int nt = blockIdx.x, jb = blockIdx.y, tid = threadIdx.x;  // (47,4)
  int w = tid>>6, lane = tid&63;
  int mt = w&1, jw = w>>1;
  int am = lane&15, aq = lane>>4;
  const __bf16* aRow = hpb + ((size_t)(nt*32 + mt*16 + am))*512 + aq*8;
  int jt = jb*2 + jw;
  const __bf16* bptr = PP + ((size_t)jt*16)*512 + lane*8;
  f32x4 acc = {0,0,0,0};
  #pragma unroll
  for (int ch = 0; ch < 16; ch++){
    bf16x8 a = *(const bf16x8*)(aRow + ch*32);
    bf16x8 b = *(const bf16x8*)(bptr + (size_t)ch*512);
    acc = __builtin_amdgcn_mfma_f32_16x16x32_bf16(a, b, acc, 0, 0, 0);
  }
  int jcol = jb*32 + jw*16 + am;
  #pragma unroll
  for (int rg=0; rg<4; rg++){
    int m = nt*32 + mt*16 + aq*4 + rg;
    rb[(size_t)m*RANK_ + jcol] = (__bf16)acc[rg];
  }
}

// ---------------- vocab GEMM: grid 500 v-chunks of 64, loop all 47 n-tiles ----------------
__global__ __launch_bounds__(256) void k_vocab2(
    const __bf16* __restrict__ rb, const __bf16* __restrict__ Eb,
    const int* __restrict__ tok,
    float* __restrict__ mpart, float* __restrict__ lpart,
    float* __restrict__ lablog)
{
  int vc = blockIdx.x, tid = threadIdx.x;
  int w = tid>>6, lane = tid&63;
  int am = lane&15, aq = lane>>4;
  int vb = vc*64 + w*16;
  bf16x8 bfr[4];
  #pragma unroll
  for (int ks=0; ks<4; ks++)
    bfr[ks] = *(const bf16x8*)(Eb + ((size_t)(vb + am))*RANK_ + ks*32 + aq*8);

  __shared__ float redM[4][32], redL[4][32];
  for (int nt = 0; nt < TS; nt++){
    f32x4 acc[2] = {{0,0,0,0},{0,0,0,0}};
    #pragma unroll
    for (int mt=0; mt<2; mt++){
      #pragma unroll
      for (int ks=0; ks<4; ks++){
        bf16x8 a = *(const bf16x8*)(rb + ((size_t)(nt*32 + mt*16 + am))*RANK_ + ks*32 + aq*8);
        acc[mt] = __builtin_amdgcn_mfma_f32_16x16x32_bf16(a, bfr[ks], acc[mt], 0,0,0);
      }
    }
    #pragma unroll
    for (int mt=0; mt<2; mt++){
      #pragma unroll
      for (int rg=0; rg<4; rg++){
        int row = mt*16 + aq*4 + rg;
        int n = nt*32 + row;
        int lbl = tok[row*T_ + nt + 1];
        float v0 = acc[mt][rg];
        if (vb + am == lbl) lablog[n] = v0;
        float m = v0;
        #pragma unroll
        for (int off=1; off<16; off<<=1) m = fmaxf(m, __shfl_xor(m, off));
        float l = expf(v0 - m);
        #pragma unroll
        for (int off=1; off<16; off<<=1) l += __shfl_xor(l, off);
        if (am == 0){ redM[w][row] = m; redL[w][row] = l; }
      }
    }
    __syncthreads();
    if (tid < 32){
      float M = fmaxf(fmaxf(redM[0][tid], redM[1][tid]), fmaxf(redM[2][tid], redM[3][tid]));
      float L = 0.f;
      #pragma unroll
      for (int ww=0; ww<4; ww++) L += redL[ww][tid]*expf(redM[ww][tid] - M);
      mpart[(size_t)(nt*32 + tid)*NVC + vc] = M;
      lpart[(size_t)(nt*32 + tid)*NVC + vc] = L;
    }
    __syncthreads();
  }
}

// ---------------- loss stage 1 ----------------
__global__ void k_loss1(const float* __restrict__ mpart, const float* __restrict__ lpart,
                        const float* __restrict__ lablog, const int* __restrict__ tgt_lens,
                        float* __restrict__ tpart){
  int t = blockIdx.x, tid = threadIdx.x;
  int row = tid >> 3, cq = tid & 7;
  int n = t*32 + row;
  float m = -1e30f;
  for (int c = cq; c < NVC; c += 8) m = fmaxf(m, mpart[(size_t)n*NVC + c]);
  #pragma unroll
  for (int off=1; off<8; off<<=1) m = fmaxf(m, __shfl_xor(m, off));
  float l = 0.f;
  for (int c = cq; c < NVC; c += 8) l += lpart[(size_t)n*NVC + c]*expf(mpart[(size_t)n*NVC + c] - m);
  #pragma unroll
  for (int off=1; off<8; off<<=1) l += __shfl_xor(l, off);
  __shared__ float red[32];
  if (cq == 0)
    red[row] = (t < tgt_lens[row] - 1) ? (m + logf(l) - lablog[n]) : 0.f;
  __syncthreads();
  if (tid == 0){
    float s = 0.f;
    #pragma unroll
    for (int i=0;i<32;i++) s += red[i];
    tpart[t] = s;
  }
}

// ---------------- loss stage 2 ----------------
__global__ void k_loss2(const float* __restrict__ tpart, float* __restrict__ out){
  int tid = threadIdx.x;
  float v = (tid < TS) ? tpart[tid] : 0.f;
  #pragma unroll
  for (int off=32; off>0; off>>=1) v += __shfl_down(v, off);
  if (tid == 0) out[0] = v;
}

extern "C" void kernel_launch(void* const* d_in, const int* in_sizes, int n_in,
                              void* d_out, int out_size, void* d_ws, size_t ws_size,
                              hipStream_t stream){
  const float* enc      = (const float*)d_in[0];
  const float* es       = (const float*)d_in[1];
  const int*   tok      = (const int*)  d_in[2];
  const int*   enc_lens = (const int*)  d_in[3];
  const int*   tgt_lens = (const int*)  d_in[4];
  const float* E        = (const float*)d_in[5];
  const float* P        = (const float*)d_in[6];
  const float* W0       = (const float*)d_in[7];
  const float* U0       = (const float*)d_in[8];
  const float* b0       = (const float*)d_in[9];
  const float* W1       = (const float*)d_in[10];
  const float* U1       = (const float*)d_in[11];
  const float* b1       = (const float*)d_in[12];
  const float* Wo       = (const float*)d_in[13];
  const float* bo       = (const float*)d_in[14];
  float* out = (float*)d_out;

  float* fb = (float*)d_ws;
  size_t fo = 0;
  float* mpart = fb + fo; fo += (size_t)TS*32*NVC;
  float* lpart = fb + fo; fo += (size_t)TS*32*NVC;
  float* lab   = fb + fo; fo += (size_t)TS*32;
  float* tpart = fb + fo; fo += 64;
  float* c0    = fb + fo; fo += 32*H_;
  float* c1    = fb + fo; fo += 32*H_;
  unsigned* bars = (unsigned*)(fb + fo); fo += 512;
  __bf16* bb = (__bf16*)(fb + fo);
  size_t bo2 = 0;
  __bf16* WP0    = bb + bo2; bo2 += (size_t)4096*2560;
  __bf16* WP1    = bb + bo2; bo2 += (size_t)4096*2048;
  __bf16* encb   = bb + bo2; bo2 += (size_t)S_*32*C_;
  __bf16* embb   = bb + bo2; bo2 += (size_t)TS*32*EMB_;
  __bf16* Eb     = bb + bo2; bo2 += (size_t)VOCAB_*RANK_;
  __bf16* rbuf   = bb + bo2; bo2 += (size_t)TS*32*RANK_;
  __bf16* WoP    = bb + bo2; bo2 += (size_t)2048*512;
  __bf16* PP     = bb + bo2; bo2 += (size_t)512*128;
  __bf16* featsb = bb + bo2; bo2 += (size_t)TS*32*2048;
  __bf16* hpb    = bb + bo2; bo2 += (size_t)TS*32*EMB_;
  __bf16* xa0a   = bb + bo2; bo2 += (size_t)32*2560;
  __bf16* xa0b   = bb + bo2; bo2 += (size_t)32*2560;
  __bf16* xa1a   = bb + bo2; bo2 += (size_t)32*2048;
  __bf16* xa1b   = bb + bo2; bo2 += (size_t)32*2048;

  k_init<<<128, 256, 0, stream>>>(es, xa0a, xa1a, c0, c1, bars);
  k_cvt<<<(S_*32*C_/4 + 255)/256, 256, 0, stream>>>(enc, encb, S_*32*C_);
  k_cvt<<<(VOCAB_*RANK_/4 + 255)/256, 256, 0, stream>>>(E, Eb, VOCAB_*RANK_);
  k_embed<<<TS*32, 128, 0, stream>>>(E, P, tok, embb, xa0a);
  k_pack<<<dim3(80,64), 256, 0, stream>>>(W0, 1536, U0, WP0, 2560, 20);
  k_pack<<<dim3(64,64), 256, 0, stream>>>(W1, 1024, U1, WP1, 2048, 16);
  k_packB<<<dim3(64,32), 64, 0, stream>>>(Wo, WoP, 2048, 512, 0);
  k_packB<<<dim3(16,8), 64, 0, stream>>>(P, PP, 512, 128, 1);

  k_loop<<<NBLK, 512, 0, stream>>>(WP0, WP1, b0, b1, c0, c1,
                                   xa0a, xa0b, xa1a, xa1b,
                                   encb, enc_lens, embb, featsb, bars);

  k_hproj_mfma<<<dim3(TS,16), 256, 0, stream>>>(featsb, WoP, bo, hpb);
  k_rproj_mfma<<<dim3(TS,4), 256, 0, stream>>>(hpb, PP, rbuf);
  k_vocab2<<<NVC, 256, 0, stream>>>(rbuf, Eb, tok, mpart, lpart, lab);
  k_loss1<<<TS, 256, 0, stream>>>(mpart, lpart, lab, tgt_lens, tpart);
  k_loss2<<<1, 64, 0, stream>>>(tpart, out);
}